// Round 2
// baseline (190.191 us; speedup 1.0000x reference)
//
#include <hip/hip_runtime.h>

#define B 64
#define N 4096
#define M 128

constexpr int T   = 256;       // threads per block
constexpr int CPB = 4;         // real columns (channels) per block -> 2 packed complex FFTs
constexpr int NB_M = M / CPB;  // 32 m-groups
constexpr int NWG  = B * NB_M; // 2048 blocks

__global__ __launch_bounds__(T, 2)
void FFTlayer_52699248722191_kernel(const float* __restrict__ x, float* __restrict__ out) {
    // 2 packed complex FFTs of length 4096, interleaved float2 (re,im)
    __shared__ float2 z[2][N];   // 64 KiB

    // chunked XCD swizzle: all 32 m-blocks of a batch land on one XCD (2 MiB slice fits 4 MiB L2)
    int bid = blockIdx.x;
    int swz = (bid & 7) * (NWG / 8) + (bid >> 3);
    int b   = swz / NB_M;
    int m0  = (swz % NB_M) * CPB;

    const float* xb = x + (size_t)b * N * M + m0;
    const int tid = threadIdx.x;

    // ---- load, bit-reversed in n (linear LDS writes -> conflict-free) ----
    for (int it = 0; it < N / T; ++it) {
        int p = tid + it * T;
        int r = (int)(__brev((unsigned)p) >> 20);   // 12-bit bit reverse
        float4 v = *(const float4*)(xb + (size_t)r * M);
        z[0][p] = make_float2(v.x, v.y);   // channels m0, m0+1 packed
        z[1][p] = make_float2(v.z, v.w);   // channels m0+2, m0+3 packed
    }
    __syncthreads();

    // ---- in-place radix-2 DIT, natural-order output ----
    const float NTWO_PI = -6.283185307179586f;
    for (int s = 1; s <= 12; ++s) {
        const int half = 1 << (s - 1);
        const float inv_m = 1.0f / (float)(1 << s);
        #pragma unroll 4
        for (int it = 0; it < 16; ++it) {
            int q = tid + it * T;         // 0..4095 task id
            int f = q >> 11;              // which packed FFT
            int j = q & 2047;             // butterfly index
            int pos = j & (half - 1);
            int i0 = ((j >> (s - 1)) << s) + pos;
            int i1 = i0 + half;
            float ang = NTWO_PI * (float)pos * inv_m;
            float sn, cs;
            __sincosf(ang, &sn, &cs);
            float2 a  = z[f][i0];
            float2 bv = z[f][i1];
            float tr = cs * bv.x - sn * bv.y;
            float ti = cs * bv.y + sn * bv.x;
            z[f][i0] = make_float2(a.x + tr, a.y + ti);
            z[f][i1] = make_float2(a.x - tr, a.y - ti);
        }
        __syncthreads();
    }

    // ---- Hermitian unpack (z = u + iv) + store ----
    float* outRe = out;
    float* outIm = out + (size_t)B * N * M;
    const size_t rowBase = (size_t)b * N * M + m0;
    for (int it = 0; it < N / T; ++it) {
        int k  = tid + it * T;
        int km = (N - k) & (N - 1);
        float4 re, im;
        {
            float2 Zk = z[0][k], Zm = z[0][km];
            re.x = 0.5f * (Zk.x + Zm.x);   // U.re  (channel m0)
            im.x = 0.5f * (Zk.y - Zm.y);   // U.im
            re.y = 0.5f * (Zk.y + Zm.y);   // V.re  (channel m0+1)
            im.y = 0.5f * (Zm.x - Zk.x);   // V.im
        }
        {
            float2 Zk = z[1][k], Zm = z[1][km];
            re.z = 0.5f * (Zk.x + Zm.x);   // channel m0+2
            im.z = 0.5f * (Zk.y - Zm.y);
            re.w = 0.5f * (Zk.y + Zm.y);   // channel m0+3
            im.w = 0.5f * (Zm.x - Zk.x);
        }
        *(float4*)(outRe + rowBase + (size_t)k * M) = re;
        *(float4*)(outIm + rowBase + (size_t)k * M) = im;
    }
}

extern "C" void kernel_launch(void* const* d_in, const int* in_sizes, int n_in,
                              void* d_out, int out_size, void* d_ws, size_t ws_size,
                              hipStream_t stream) {
    const float* x = (const float*)d_in[0];
    float* out = (float*)d_out;
    FFTlayer_52699248722191_kernel<<<NWG, T, 0, stream>>>(x, out);
}

// Round 3
// 162.661 us; speedup vs baseline: 1.1692x; 1.1692x over previous
//
#include <hip/hip_runtime.h>

#define B 64
#define N 4096
#define M 128

constexpr int T    = 512;      // threads per block (8 waves)
constexpr int CPB  = 4;        // real channels per block -> 2 packed complex FFTs
constexpr int NB_M = M / CPB;  // 32
constexpr int NWG  = B * NB_M; // 2048 blocks

// XOR fold of high index bits into low 4 bits: spreads stride-L butterfly
// patterns over all 16 bank-pairs (float2 elements). Bijective (high bits kept).
__device__ __forceinline__ int sw(int p) {
    return (p & ~15) | ((p ^ (p >> 4) ^ (p >> 8)) & 15);
}

__device__ __forceinline__ float2 cadd(float2 a, float2 b){ return make_float2(a.x+b.x, a.y+b.y); }
__device__ __forceinline__ float2 csub(float2 a, float2 b){ return make_float2(a.x-b.x, a.y-b.y); }
__device__ __forceinline__ float2 cmul(float2 a, float2 b){ return make_float2(a.x*b.x - a.y*b.y, a.x*b.y + a.y*b.x); }
__device__ __forceinline__ float2 mulnegi(float2 a){ return make_float2(a.y, -a.x); }  // *(-i)
__device__ __forceinline__ float2 muli(float2 a)  { return make_float2(-a.y, a.x); }   // *(+i)

// forward DFT8 in place (W8 = e^{-i pi/4})
__device__ __forceinline__ void dft8(float2 t[8]) {
    float2 e0=cadd(t[0],t[4]), e1=csub(t[0],t[4]);
    float2 e2=cadd(t[2],t[6]), e3=csub(t[2],t[6]);
    float2 E0=cadd(e0,e2), E2=csub(e0,e2);
    float2 E1=cadd(e1,mulnegi(e3)), E3=cadd(e1,muli(e3));
    float2 o0=cadd(t[1],t[5]), o1=csub(t[1],t[5]);
    float2 o2=cadd(t[3],t[7]), o3=csub(t[3],t[7]);
    float2 O0=cadd(o0,o2), O2=csub(o0,o2);
    float2 O1=cadd(o1,mulnegi(o3)), O3=cadd(o1,muli(o3));
    const float C = 0.70710678118654752f;
    float2 w1O1 = make_float2(C*(O1.x+O1.y), C*(O1.y-O1.x));   // W8^1 * O1
    float2 w2O2 = mulnegi(O2);                                  // W8^2 * O2
    float2 w3O3 = make_float2(C*(O3.y-O3.x), -C*(O3.x+O3.y));  // W8^3 * O3
    t[0]=cadd(E0,O0);   t[4]=csub(E0,O0);
    t[1]=cadd(E1,w1O1); t[5]=csub(E1,w1O1);
    t[2]=cadd(E2,w2O2); t[6]=csub(E2,w2O2);
    t[3]=cadd(E3,w3O3); t[7]=csub(E3,w3O3);
}

// one radix-8 DIT stage over LDS, span L (stage combines k*L strides).
// tid in [0,512): butterfly q=tid for both packed FFTs; twiddles shared.
template<int L>
__device__ __forceinline__ void stage(float2 (*z)[N], int tid) {
    const int j = tid & (L - 1);
    const int G = tid / L;
    const int base = G * 8 * L + j;
    float2 w1;
    {
        float sn, cs;
        __sincosf(-6.2831853071795864f * (float)j / (float)(8 * L), &sn, &cs);
        w1 = make_float2(cs, sn);
    }
    float2 w[8];
    w[1] = w1;
    #pragma unroll
    for (int k = 2; k < 8; ++k) w[k] = cmul(w[k-1], w1);
    int idx[8];
    #pragma unroll
    for (int k = 0; k < 8; ++k) idx[k] = sw(base + k * L);
    #pragma unroll
    for (int f = 0; f < 2; ++f) {
        float2 t[8];
        #pragma unroll
        for (int k = 0; k < 8; ++k) t[k] = z[f][idx[k]];
        #pragma unroll
        for (int k = 1; k < 8; ++k) t[k] = cmul(t[k], w[k]);
        dft8(t);
        #pragma unroll
        for (int k = 0; k < 8; ++k) z[f][idx[k]] = t[k];
    }
}

__global__ __launch_bounds__(T, 4)
void FFTlayer_52699248722191_kernel(const float* __restrict__ x, float* __restrict__ out) {
    __shared__ float2 z[2][N];   // 64 KiB, 2 packed FFTs

    int bid = blockIdx.x;
    int swz = (bid & 7) * (NWG / 8) + (bid >> 3);   // XCD-chunked swizzle
    int b   = swz / NB_M;
    int m0  = (swz % NB_M) * CPB;

    const float* xb = x + (size_t)b * N * M + m0;
    const int tid = threadIdx.x;

    // ---- stage 1 (L=1) fused with the global gather: digit-reversed rows ----
    {
        const int G = tid;                                   // 0..511
        const int c = ((G & 7) << 6) | (G & 56) | (G >> 6);  // octal-digit reverse
        float2 ta[8], tb[8];
        #pragma unroll
        for (int k = 0; k < 8; ++k) {
            float4 v = *(const float4*)(xb + (size_t)(k * 512 + c) * M);
            ta[k] = make_float2(v.x, v.y);
            tb[k] = make_float2(v.z, v.w);
        }
        dft8(ta);
        dft8(tb);
        #pragma unroll
        for (int k = 0; k < 8; ++k) {
            int d = sw(8 * G + k);
            z[0][d] = ta[k];
            z[1][d] = tb[k];
        }
    }
    __syncthreads();
    stage<8>(z, tid);     // L=8   (twiddle denom 64)
    __syncthreads();
    stage<64>(z, tid);    // L=64  (denom 512)
    __syncthreads();
    stage<512>(z, tid);   // L=512 (denom 4096)
    __syncthreads();

    // ---- Hermitian unpack (z = u + iv) + store ----
    float* outRe = out;
    float* outIm = out + (size_t)B * N * M;
    const size_t rowBase = (size_t)b * N * M + m0;
    #pragma unroll
    for (int it = 0; it < N / T; ++it) {
        int k  = tid + it * T;
        int km = (N - k) & (N - 1);
        int a0 = sw(k), a1 = sw(km);
        float4 re, im;
        {
            float2 Zk = z[0][a0], Zm = z[0][a1];
            re.x = 0.5f * (Zk.x + Zm.x);
            im.x = 0.5f * (Zk.y - Zm.y);
            re.y = 0.5f * (Zk.y + Zm.y);
            im.y = 0.5f * (Zm.x - Zk.x);
        }
        {
            float2 Zk = z[1][a0], Zm = z[1][a1];
            re.z = 0.5f * (Zk.x + Zm.x);
            im.z = 0.5f * (Zk.y - Zm.y);
            re.w = 0.5f * (Zk.y + Zm.y);
            im.w = 0.5f * (Zm.x - Zk.x);
        }
        *(float4*)(outRe + rowBase + (size_t)k * M) = re;
        *(float4*)(outIm + rowBase + (size_t)k * M) = im;
    }
}

extern "C" void kernel_launch(void* const* d_in, const int* in_sizes, int n_in,
                              void* d_out, int out_size, void* d_ws, size_t ws_size,
                              hipStream_t stream) {
    const float* x = (const float*)d_in[0];
    float* out = (float*)d_out;
    FFTlayer_52699248722191_kernel<<<NWG, T, 0, stream>>>(x, out);
}